// Round 1
// baseline (2360.876 us; speedup 1.0000x reference)
//
#include <hip/hip_runtime.h>

#define NN 160            // N == L
#define MAT (NN*NN)       // 25600 floats per (b,c) matrix
#define BCN 1024          // B*C
#define BIG ((size_t)BCN * MAT)   // 26,214,400 floats
#define ALPHA 0.05f
#define BETA 0.95f
#define LT_HOP 32
#define LT_G 40

// ---------------------------------------------------------------------------
// prep: At1[w][v] = A1[v][w], At2[w][v] = A2[v][w], aT[w][v] = a[v][w]
// A1 = rownorm(a + I), A2 = rownorm(a.T + I)
// ---------------------------------------------------------------------------
__global__ void prep_adj(const float* __restrict__ a, float* __restrict__ At1,
                         float* __restrict__ At2, float* __restrict__ aT)
{
    __shared__ float rs[NN], cs[NN];
    int t = threadIdx.x;
    if (t < NN) {
        float r = 0.f, c = 0.f;
        for (int w = 0; w < NN; ++w) { r += a[t*NN + w]; c += a[w*NN + t]; }
        rs[t] = 1.f / (r + 1.f);
        cs[t] = 1.f / (c + 1.f);
    }
    __syncthreads();
    for (int i = t; i < MAT; i += blockDim.x) {
        int w = i / NN, v = i % NN;         // output layout [w][v]
        float avw = a[v*NN + w];
        float awv = a[w*NN + v];
        float d = (v == w) ? 1.f : 0.f;
        At1[i] = (avw + d) * rs[v];
        At2[i] = (awv + d) * cs[v];
        aT[i]  = avw;
    }
}

// ---------------------------------------------------------------------------
// double_hop: per (bc, l-tile of 32):
//   t1 = a*x + b*A@x   -> g1 (+= if accumulate)
//   t2 = a*x + b*A@t1  -> g2 (+= if accumulate)
// At is the transposed normalized adjacency: At[w*NN+v] = A[v][w].
// Single LDS tile reused (x-tile, then t1-tile); each thread keeps its own
// x values in registers for the blends. l-columns are independent, so the
// tiling is race-free.
// ---------------------------------------------------------------------------
__global__ __launch_bounds__(256) void double_hop(
    const float* __restrict__ x, const float* __restrict__ At,
    float* __restrict__ g1, float* __restrict__ g2, int accumulate)
{
    __shared__ float hs[NN * LT_HOP];   // 20,480 B
    int bc = blockIdx.x / 5;
    int l0 = (blockIdx.x % 5) * LT_HOP;
    const float* xb = x + (size_t)bc * MAT;
    int t = threadIdx.x;

    for (int i4 = t; i4 < NN*LT_HOP/4; i4 += 256) {
        int w  = i4 / (LT_HOP/4);
        int li = (i4 % (LT_HOP/4)) * 4;
        *(float4*)&hs[w*LT_HOP + li] = *(const float4*)&xb[w*NN + l0 + li];
    }
    __syncthreads();

    int lg = (t % 8) * 4;       // l offset within tile
    int v0 = (t / 8) * 5;       // 5 consecutive output rows

    float4 acc[5], xv[5];
    #pragma unroll
    for (int j = 0; j < 5; ++j) acc[j] = make_float4(0.f,0.f,0.f,0.f);

    for (int w = 0; w < NN; ++w) {
        float4 h4 = *(float4*)&hs[w*LT_HOP + lg];
        #pragma unroll
        for (int j = 0; j < 5; ++j) {
            float av = At[w*NN + v0 + j];
            acc[j].x = fmaf(av, h4.x, acc[j].x);
            acc[j].y = fmaf(av, h4.y, acc[j].y);
            acc[j].z = fmaf(av, h4.z, acc[j].z);
            acc[j].w = fmaf(av, h4.w, acc[j].w);
        }
    }
    #pragma unroll
    for (int j = 0; j < 5; ++j) xv[j] = *(float4*)&hs[(v0+j)*LT_HOP + lg];
    __syncthreads();   // all reads of x-tile done

    size_t gb = (size_t)bc * MAT + l0 + lg;
    float4 t1[5];
    #pragma unroll
    for (int j = 0; j < 5; ++j) {
        t1[j].x = fmaf(BETA, acc[j].x, ALPHA * xv[j].x);
        t1[j].y = fmaf(BETA, acc[j].y, ALPHA * xv[j].y);
        t1[j].z = fmaf(BETA, acc[j].z, ALPHA * xv[j].z);
        t1[j].w = fmaf(BETA, acc[j].w, ALPHA * xv[j].w);
        *(float4*)&hs[(v0+j)*LT_HOP + lg] = t1[j];
        float4 o = t1[j];
        float* gp = &g1[gb + (size_t)(v0+j)*NN];
        if (accumulate) {
            float4 r = *(const float4*)gp;
            o.x += r.x; o.y += r.y; o.z += r.z; o.w += r.w;
        }
        *(float4*)gp = o;
    }
    __syncthreads();   // t1-tile visible

    #pragma unroll
    for (int j = 0; j < 5; ++j) acc[j] = make_float4(0.f,0.f,0.f,0.f);
    for (int w = 0; w < NN; ++w) {
        float4 h4 = *(float4*)&hs[w*LT_HOP + lg];
        #pragma unroll
        for (int j = 0; j < 5; ++j) {
            float av = At[w*NN + v0 + j];
            acc[j].x = fmaf(av, h4.x, acc[j].x);
            acc[j].y = fmaf(av, h4.y, acc[j].y);
            acc[j].z = fmaf(av, h4.z, acc[j].z);
            acc[j].w = fmaf(av, h4.w, acc[j].w);
        }
    }
    #pragma unroll
    for (int j = 0; j < 5; ++j) {
        float4 o;
        o.x = fmaf(BETA, acc[j].x, ALPHA * xv[j].x);
        o.y = fmaf(BETA, acc[j].y, ALPHA * xv[j].y);
        o.z = fmaf(BETA, acc[j].z, ALPHA * xv[j].z);
        o.w = fmaf(BETA, acc[j].w, ALPHA * xv[j].w);
        float* gp = &g2[gb + (size_t)(v0+j)*NN];
        if (accumulate) {
            float4 r = *(const float4*)gp;
            o.x += r.x; o.y += r.y; o.z += r.z; o.w += r.w;
        }
        *(float4*)gp = o;
    }
}

// ---------------------------------------------------------------------------
// chanmix: embed[b,o,v,l] = 2be[o] + sum_c 2x*We[o][c] + g1*We[o][32+c] + g2*We[o][64+c]
//          pool likewise with Wp/bp. Each thread does positions (b,v,l) and (b,v+80,l).
// ---------------------------------------------------------------------------
__global__ __launch_bounds__(256) void chanmix(
    const float* __restrict__ x, const float* __restrict__ g1, const float* __restrict__ g2,
    const float* __restrict__ We, const float* __restrict__ be,
    const float* __restrict__ Wp, const float* __restrict__ bp,
    float* __restrict__ embed, float* __restrict__ pool)
{
    int idx = blockIdx.x * 256 + threadIdx.x;   // 409,600 threads
    int l = idx % NN;
    int v = (idx / NN) % 80;
    int b = idx / (NN * 80);
    size_t base = (size_t)b * (32*MAT) + (size_t)v * NN + l;
    const size_t coff = MAT;
    const size_t voff = (size_t)80 * NN;

    float e0[32], e1[32], p0[32], p1[32];
    #pragma unroll
    for (int o = 0; o < 32; ++o) {
        float b2e = 2.f * be[o], b2p = 2.f * bp[o];
        e0[o] = b2e; e1[o] = b2e; p0[o] = b2p; p1[o] = b2p;
    }
    #pragma unroll 1
    for (int k = 0; k < 3; ++k) {
        const float* s = (k == 0) ? x : ((k == 1) ? g1 : g2);
        float sc = (k == 0) ? 2.f : 1.f;
        #pragma unroll 1
        for (int c = 0; c < 32; ++c) {
            float h0 = s[base + (size_t)c*coff] * sc;
            float h1 = s[base + voff + (size_t)c*coff] * sc;
            #pragma unroll
            for (int o = 0; o < 32; ++o) {
                float we = We[o*96 + k*32 + c];
                float wp = Wp[o*96 + k*32 + c];
                e0[o] = fmaf(we, h0, e0[o]);
                e1[o] = fmaf(we, h1, e1[o]);
                p0[o] = fmaf(wp, h0, p0[o]);
                p1[o] = fmaf(wp, h1, p1[o]);
            }
        }
    }
    #pragma unroll
    for (int o = 0; o < 32; ++o) {
        embed[base + (size_t)o*coff]        = e0[o];
        embed[base + voff + (size_t)o*coff] = e1[o];
        pool [base + (size_t)o*coff]        = p0[o];
        pool [base + voff + (size_t)o*coff] = p1[o];
    }
}

// ---------------------------------------------------------------------------
// softmax over node dim (axis 2), in place. One thread per (b,o,l) column.
// ---------------------------------------------------------------------------
__global__ __launch_bounds__(256) void softmax_n(float* __restrict__ p)
{
    int idx = blockIdx.x * 256 + threadIdx.x;   // 163,840 columns
    int l  = idx % NN;
    int bo = idx / NN;
    float* col = p + (size_t)bo * MAT + l;
    float m = -1e30f, s = 0.f;
    for (int n = 0; n < NN; ++n) {
        float v  = col[(size_t)n * NN];
        float mn = fmaxf(m, v);
        s = s * __expf(m - mn) + __expf(v - mn);
        m = mn;
    }
    float inv = 1.f / s;
    for (int n = 0; n < NN; ++n) {
        float v = col[(size_t)n * NN];
        col[(size_t)n * NN] = __expf(v - m) * inv;
    }
}

// ---------------------------------------------------------------------------
// generic per-bc GEMM: C[bc][v][l] = sum_w P(v,w) * Q[bc][w][l]
//   ptrans=1: P(v,w) = Pb[w*NN+v] (contiguous inner loads)
//   ptrans=0: P(v,w) = Pb[v*NN+w]
//   pstride = 0 for a shared P, MAT for per-bc P.
// ---------------------------------------------------------------------------
__global__ __launch_bounds__(320) void gemm_pq(
    const float* __restrict__ P, long pstride, int ptrans,
    const float* __restrict__ Q, float* __restrict__ C)
{
    __shared__ float qs[NN * LT_G];   // 25,600 B
    int bc = blockIdx.x >> 2;
    int l0 = (blockIdx.x & 3) * LT_G;
    const float* Qb = Q + (size_t)bc * MAT;
    const float* Pb = P + (size_t)bc * (size_t)pstride;
    float* Cb = C + (size_t)bc * MAT;
    int t = threadIdx.x;

    for (int i4 = t; i4 < NN*LT_G/4; i4 += 320) {
        int w  = i4 / (LT_G/4);
        int li = (i4 % (LT_G/4)) * 4;
        *(float4*)&qs[w*LT_G + li] = *(const float4*)&Qb[w*NN + l0 + li];
    }
    __syncthreads();

    int lg = (t % 10) * 4;
    int v0 = (t / 10) * 5;
    float4 acc[5];
    #pragma unroll
    for (int j = 0; j < 5; ++j) acc[j] = make_float4(0.f,0.f,0.f,0.f);

    if (ptrans) {
        for (int w = 0; w < NN; ++w) {
            float4 q4 = *(float4*)&qs[w*LT_G + lg];
            #pragma unroll
            for (int j = 0; j < 5; ++j) {
                float pv = Pb[w*NN + v0 + j];
                acc[j].x = fmaf(pv, q4.x, acc[j].x);
                acc[j].y = fmaf(pv, q4.y, acc[j].y);
                acc[j].z = fmaf(pv, q4.z, acc[j].z);
                acc[j].w = fmaf(pv, q4.w, acc[j].w);
            }
        }
    } else {
        for (int w = 0; w < NN; ++w) {
            float4 q4 = *(float4*)&qs[w*LT_G + lg];
            #pragma unroll
            for (int j = 0; j < 5; ++j) {
                float pv = Pb[(v0+j)*NN + w];
                acc[j].x = fmaf(pv, q4.x, acc[j].x);
                acc[j].y = fmaf(pv, q4.y, acc[j].y);
                acc[j].z = fmaf(pv, q4.z, acc[j].z);
                acc[j].w = fmaf(pv, q4.w, acc[j].w);
            }
        }
    }
    #pragma unroll
    for (int j = 0; j < 5; ++j)
        *(float4*)&Cb[(size_t)(v0+j)*NN + l0 + lg] = acc[j];
}

// ---------------------------------------------------------------------------
extern "C" void kernel_launch(void* const* d_in, const int* in_sizes, int n_in,
                              void* d_out, int out_size, void* d_ws, size_t ws_size,
                              hipStream_t stream)
{
    const float* x  = (const float*)d_in[0];
    const float* a  = (const float*)d_in[1];
    const float* We = (const float*)d_in[2];
    const float* be = (const float*)d_in[3];
    const float* Wp = (const float*)d_in[4];
    const float* bp = (const float*)d_in[5];

    float* part0 = (float*)d_out;          // pool -> s -> x_new
    float* part1 = part0 + BIG;            // embed -> a_new

    float* ws  = (float*)d_ws;
    float* At1 = ws;                       // 25,600
    float* At2 = ws + MAT;                 // 25,600
    float* aT  = ws + 2*MAT;               // 25,600
    float* g1  = ws + 3*MAT;               // BIG
    float* g2  = g1 + BIG;                 // BIG
    // total ws need: (3*25600 + 2*26214400)*4 = 210,022,400 bytes

    prep_adj<<<1, 256, 0, stream>>>(a, At1, At2, aT);
    // pass 1 (A from a):      g1 = h1_a,        g2 = h2_a
    double_hop<<<5120, 256, 0, stream>>>(x, At1, g1, g2, 0);
    // pass 2 (A from a.T):    g1 += h1_aT,      g2 += h2_aT
    double_hop<<<5120, 256, 0, stream>>>(x, At2, g1, g2, 1);
    // embed -> part1, pool -> part0
    chanmix<<<1600, 256, 0, stream>>>(x, g1, g2, We, be, Wp, bp, part1, part0);
    // s = softmax(pool) in place
    softmax_n<<<640, 256, 0, stream>>>(part0);
    // keep a copy of s (g2 is free now) so outputs can overwrite d_out
    hipMemcpyAsync(g2, part0, BIG * sizeof(float), hipMemcpyDeviceToDevice, stream);
    // M = a @ s  -> g1   (g1 free after chanmix)
    gemm_pq<<<4096, 320, 0, stream>>>(aT, 0, 1, part0, g1);
    // x_new = s^T @ embed -> part0 (s preserved in g2)
    gemm_pq<<<4096, 320, 0, stream>>>(g2, (long)MAT, 1, part1, part0);
    // a_new = s @ M -> part1 (embed dead)
    gemm_pq<<<4096, 320, 0, stream>>>(g2, (long)MAT, 0, g1, part1);
}

// Round 2
// 1708.089 us; speedup vs baseline: 1.3822x; 1.3822x over previous
//
#include <hip/hip_runtime.h>

#define NN 160            // N == L
#define MAT (NN*NN)       // 25600 floats per (b,c) matrix
#define BCN 1024          // B*C
#define BIG ((size_t)BCN * MAT)   // 26,214,400 floats
#define ALPHA 0.05f
#define BETA 0.95f
#define BK 16
#define PSTR 164          // padded LDS row stride (164%32=4 -> conflict-free)

// mode bits for bgemm epilogue
#define M_BLEND 1   // out = 0.05*x + 0.95*acc
#define M_ACC   2   // out += C_prev
#define M_AUX   4   // aux += out

// ---------------------------------------------------------------------------
// prep_sums: block b computes rs[b] = 1/(rowsum_b(a)+1), cs[b] = 1/(colsum_b(a)+1)
// sums[0..159] = rs, sums[160..319] = cs
// ---------------------------------------------------------------------------
__global__ __launch_bounds__(256) void prep_sums(const float* __restrict__ a,
                                                 float* __restrict__ sums)
{
    __shared__ float rbuf[256], cbuf[256];
    int b = blockIdx.x;        // 0..159
    int t = threadIdx.x;
    float r = 0.f, c = 0.f;
    if (t < NN) { r = a[b*NN + t]; c = a[t*NN + b]; }
    rbuf[t] = r; cbuf[t] = c;
    __syncthreads();
    for (int s = 128; s > 0; s >>= 1) {
        if (t < s) { rbuf[t] += rbuf[t+s]; cbuf[t] += cbuf[t+s]; }
        __syncthreads();
    }
    if (t == 0) {
        sums[b]      = 1.f / (rbuf[0] + 1.f);
        sums[NN + b] = 1.f / (cbuf[0] + 1.f);
    }
}

// ---------------------------------------------------------------------------
// prep_fill: At1[w][v] = A1[v][w], At2[w][v] = A2[v][w], aT[w][v] = a[v][w]
// A1 = rownorm(a + I), A2 = rownorm(a.T + I). grid 100 x 256 = 25600 exact.
// ---------------------------------------------------------------------------
__global__ __launch_bounds__(256) void prep_fill(
    const float* __restrict__ a, const float* __restrict__ sums,
    float* __restrict__ At1, float* __restrict__ At2, float* __restrict__ aT)
{
    int i = blockIdx.x * 256 + threadIdx.x;   // [w][v]
    int w = i / NN, v = i % NN;
    float avw = a[v*NN + w];
    float awv = a[w*NN + v];
    float d = (v == w) ? 1.f : 0.f;
    At1[i] = (avw + d) * sums[v];
    At2[i] = (awv + d) * sums[NN + v];
    aT[i]  = avw;
}

// ---------------------------------------------------------------------------
// bgemm: per-block one bc; C[bc][v][l] = epilogue( sum_w P(v,w) * Q[bc][w][l] )
//   ptrans=1: P stored [w][v] (P(v,w) = Pb[w*NN+v]) — direct float4 staging
//   ptrans=0: P stored [v][w] — transposing stage (scalar LDS writes, <=2-way)
//   pstride:  0 = shared P, MAT = per-bc P
// Thread tile 10x10, block tile 160x160, BK=16 K-chunks in LDS.
// ---------------------------------------------------------------------------
__global__ __launch_bounds__(256) void bgemm(
    const float* __restrict__ P, long pstride, int ptrans,
    const float* __restrict__ Q, float* __restrict__ C,
    const float* __restrict__ xb, float* __restrict__ aux, int mode)
{
    __shared__ float pt[BK * PSTR];   // 10,496 B
    __shared__ float qs[BK * PSTR];   // 10,496 B
    int bc = blockIdx.x;
    int t  = threadIdx.x;
    const float* Pb = P + (size_t)bc * (size_t)pstride;
    const float* Qb = Q + (size_t)bc * MAT;
    int tx = t & 15, ty = t >> 4;
    int l0 = tx * 10, v0 = ty * 10;

    float2 acc[10][5];
    #pragma unroll
    for (int r = 0; r < 10; ++r)
        #pragma unroll
        for (int c = 0; c < 5; ++c) acc[r][c] = make_float2(0.f, 0.f);

    for (int kk = 0; kk < NN; kk += BK) {
        if (ptrans) {
            for (int i = t; i < 640; i += 256) {
                int wk = i / 40, f = (i % 40) * 4;
                *(float4*)&pt[wk*PSTR + f] = *(const float4*)&Pb[(kk+wk)*NN + f];
            }
        } else {
            for (int i = t; i < 640; i += 256) {
                int v = i >> 2, g = (i & 3) * 4;
                float4 p4 = *(const float4*)&Pb[v*NN + kk + g];
                pt[(g+0)*PSTR + v] = p4.x;
                pt[(g+1)*PSTR + v] = p4.y;
                pt[(g+2)*PSTR + v] = p4.z;
                pt[(g+3)*PSTR + v] = p4.w;
            }
        }
        for (int i = t; i < 640; i += 256) {
            int wk = i / 40, f = (i % 40) * 4;
            *(float4*)&qs[wk*PSTR + f] = *(const float4*)&Qb[(kk+wk)*NN + f];
        }
        __syncthreads();
        #pragma unroll 2
        for (int wk = 0; wk < BK; ++wk) {
            float pa[10]; float2 qb[5];
            #pragma unroll
            for (int r = 0; r < 5; ++r) {
                float2 p2 = *(float2*)&pt[wk*PSTR + v0 + 2*r];
                pa[2*r] = p2.x; pa[2*r+1] = p2.y;
            }
            #pragma unroll
            for (int c = 0; c < 5; ++c)
                qb[c] = *(float2*)&qs[wk*PSTR + l0 + 2*c];
            #pragma unroll
            for (int r = 0; r < 10; ++r)
                #pragma unroll
                for (int c = 0; c < 5; ++c) {
                    acc[r][c].x = fmaf(pa[r], qb[c].x, acc[r][c].x);
                    acc[r][c].y = fmaf(pa[r], qb[c].y, acc[r][c].y);
                }
        }
        __syncthreads();
    }

    float* Cb = C + (size_t)bc * MAT;
    #pragma unroll
    for (int r = 0; r < 10; ++r) {
        size_t row = (size_t)(v0 + r) * NN + l0;
        #pragma unroll
        for (int c = 0; c < 5; ++c) {
            float2 o = acc[r][c];
            if (mode & M_BLEND) {
                const float* xbb = xb + (size_t)bc * MAT;
                float2 xv = *(const float2*)&xbb[row + 2*c];
                o.x = fmaf(BETA, o.x, ALPHA * xv.x);
                o.y = fmaf(BETA, o.y, ALPHA * xv.y);
            }
            if (mode & M_ACC) {
                float2 pr = *(const float2*)&Cb[row + 2*c];
                o.x += pr.x; o.y += pr.y;
            }
            *(float2*)&Cb[row + 2*c] = o;
            if (mode & M_AUX) {
                float* auxb = aux + (size_t)bc * MAT;
                float2 av = *(const float2*)&auxb[row + 2*c];
                av.x += o.x; av.y += o.y;
                *(float2*)&auxb[row + 2*c] = av;
            }
        }
    }
}

// ---------------------------------------------------------------------------
// chanmix: embed[b,o,v,l] = 2be[o] + sum_c 2x*We[o][c] + g1*We[o][32+c] + g2*We[o][64+c]
//          pool likewise with Wp/bp. Each thread does (b,v,l) and (b,v+80,l).
// ---------------------------------------------------------------------------
__global__ __launch_bounds__(256) void chanmix(
    const float* __restrict__ x, const float* __restrict__ g1, const float* __restrict__ g2,
    const float* __restrict__ We, const float* __restrict__ be,
    const float* __restrict__ Wp, const float* __restrict__ bp,
    float* __restrict__ embed, float* __restrict__ pool)
{
    int idx = blockIdx.x * 256 + threadIdx.x;   // 409,600 threads
    int l = idx % NN;
    int v = (idx / NN) % 80;
    int b = idx / (NN * 80);
    size_t base = (size_t)b * (32*MAT) + (size_t)v * NN + l;
    const size_t coff = MAT;
    const size_t voff = (size_t)80 * NN;

    float e0[32], e1[32], p0[32], p1[32];
    #pragma unroll
    for (int o = 0; o < 32; ++o) {
        float b2e = 2.f * be[o], b2p = 2.f * bp[o];
        e0[o] = b2e; e1[o] = b2e; p0[o] = b2p; p1[o] = b2p;
    }
    #pragma unroll 1
    for (int k = 0; k < 3; ++k) {
        const float* s = (k == 0) ? x : ((k == 1) ? g1 : g2);
        float sc = (k == 0) ? 2.f : 1.f;
        #pragma unroll 1
        for (int c = 0; c < 32; ++c) {
            float h0 = s[base + (size_t)c*coff] * sc;
            float h1 = s[base + voff + (size_t)c*coff] * sc;
            #pragma unroll
            for (int o = 0; o < 32; ++o) {
                float we = We[o*96 + k*32 + c];
                float wp = Wp[o*96 + k*32 + c];
                e0[o] = fmaf(we, h0, e0[o]);
                e1[o] = fmaf(we, h1, e1[o]);
                p0[o] = fmaf(wp, h0, p0[o]);
                p1[o] = fmaf(wp, h1, p1[o]);
            }
        }
    }
    #pragma unroll
    for (int o = 0; o < 32; ++o) {
        embed[base + (size_t)o*coff]        = e0[o];
        embed[base + voff + (size_t)o*coff] = e1[o];
        pool [base + (size_t)o*coff]        = p0[o];
        pool [base + voff + (size_t)o*coff] = p1[o];
    }
}

// ---------------------------------------------------------------------------
// softmax over node dim (axis 2), in place. One thread per (b,o,l) column.
// ---------------------------------------------------------------------------
__global__ __launch_bounds__(256) void softmax_n(float* __restrict__ p)
{
    int idx = blockIdx.x * 256 + threadIdx.x;   // 163,840 columns
    int l  = idx % NN;
    int bo = idx / NN;
    float* col = p + (size_t)bo * MAT + l;
    float m = -1e30f, s = 0.f;
    for (int n = 0; n < NN; ++n) {
        float v  = col[(size_t)n * NN];
        float mn = fmaxf(m, v);
        s = s * __expf(m - mn) + __expf(v - mn);
        m = mn;
    }
    float inv = 1.f / s;
    for (int n = 0; n < NN; ++n) {
        float v = col[(size_t)n * NN];
        col[(size_t)n * NN] = __expf(v - m) * inv;
    }
}

// ---------------------------------------------------------------------------
extern "C" void kernel_launch(void* const* d_in, const int* in_sizes, int n_in,
                              void* d_out, int out_size, void* d_ws, size_t ws_size,
                              hipStream_t stream)
{
    const float* x  = (const float*)d_in[0];
    const float* a  = (const float*)d_in[1];
    const float* We = (const float*)d_in[2];
    const float* be = (const float*)d_in[3];
    const float* Wp = (const float*)d_in[4];
    const float* bp = (const float*)d_in[5];

    float* part0 = (float*)d_out;          // h1b scratch -> pool -> s -> x_new
    float* part1 = part0 + BIG;            // embed -> a_new

    float* ws   = (float*)d_ws;
    float* At1  = ws;                      // MAT
    float* At2  = ws + MAT;                // MAT
    float* aT   = ws + 2*MAT;              // MAT
    float* B1   = ws + 3*MAT;              // BIG: h1a -> G1 -> M
    float* B2   = B1 + BIG;                // BIG: h2a -> G2 -> s-copy
    float* sums = B1;                      // 320 floats, dead before B1's first use
    // ws need: (3*25600 + 2*26214400)*4 = 210,022,400 bytes (same as round 1)

    prep_sums<<<160, 256, 0, stream>>>(a, sums);
    prep_fill<<<100, 256, 0, stream>>>(a, sums, At1, At2, aT);

    // hop chain (4 batched GEMMs with fused blend/acc epilogues):
    // B1 = h1a = blend(x, A1@x)
    bgemm<<<BCN, 256, 0, stream>>>(At1, 0, 1, x,     B1,    x, nullptr, M_BLEND);
    // B2 = h2a = blend(x, A1@h1a)
    bgemm<<<BCN, 256, 0, stream>>>(At1, 0, 1, B1,    B2,    x, nullptr, M_BLEND);
    // part0 = h1b = blend(x, A2@x);  B1 += h1b  (B1 -> G1)
    bgemm<<<BCN, 256, 0, stream>>>(At2, 0, 1, x,     part0, x, B1,      M_BLEND|M_AUX);
    // B2 += blend(x, A2@h1b)  (B2 -> G2)
    bgemm<<<BCN, 256, 0, stream>>>(At2, 0, 1, part0, B2,    x, nullptr, M_BLEND|M_ACC);

    // embed -> part1, pool -> part0
    chanmix<<<1600, 256, 0, stream>>>(x, B1, B2, We, be, Wp, bp, part1, part0);
    // s = softmax(pool) in place
    softmax_n<<<640, 256, 0, stream>>>(part0);
    // keep a copy of s (B2 free now) so x_new can overwrite part0
    hipMemcpyAsync(B2, part0, BIG * sizeof(float), hipMemcpyDeviceToDevice, stream);

    // M = a@s -> B1
    bgemm<<<BCN, 256, 0, stream>>>(aT, 0,         1, part0, B1,    nullptr, nullptr, 0);
    // x_new = s^T @ embed -> part0 (s preserved in B2)
    bgemm<<<BCN, 256, 0, stream>>>(B2, (long)MAT, 1, part1, part0, nullptr, nullptr, 0);
    // a_new = s @ M -> part1 (embed dead)
    bgemm<<<BCN, 256, 0, stream>>>(B2, (long)MAT, 0, B1,    part1, nullptr, nullptr, 0);
}

// Round 3
// 870.162 us; speedup vs baseline: 2.7131x; 1.9630x over previous
//
#include <hip/hip_runtime.h>

#define NN 160
#define MAT (NN*NN)            // 25600
#define BCN 1024               // B*C
#define BIG ((size_t)BCN * MAT)
#define PKSZ 12800             // uints per bc in PK layout: 20 k8-groups * 160 * 4
#define ALPHA 0.05f
#define BETA  0.95f

typedef unsigned int u32;
typedef __attribute__((ext_vector_type(8))) short short8;   // 8 bf16 = 4 VGPRs
typedef __attribute__((ext_vector_type(4))) float f32x4;

// pack two fp32 -> bf16 pair (RNE), lo in low 16, hi in high 16
static __device__ __forceinline__ u32 pk2(float lo, float hi) {
    u32 a = __float_as_uint(lo), b = __float_as_uint(hi);
    a += 0x7fffu + ((a >> 16) & 1u);
    b += 0x7fffu + ((b >> 16) & 1u);
    return (a >> 16) | (b & 0xffff0000u);
}

// ---------------------------------------------------------------------------
// prep_sums: sums[v] = 1/(rowsum_v(a)+1), sums[160+v] = 1/(colsum_v(a)+1)
// ---------------------------------------------------------------------------
__global__ __launch_bounds__(256) void prep_sums(const float* __restrict__ a,
                                                 float* __restrict__ sums)
{
    __shared__ float rbuf[256], cbuf[256];
    int b = blockIdx.x, t = threadIdx.x;
    float r = 0.f, c = 0.f;
    if (t < NN) { r = a[b*NN + t]; c = a[t*NN + b]; }
    rbuf[t] = r; cbuf[t] = c;
    __syncthreads();
    for (int s = 128; s > 0; s >>= 1) {
        if (t < s) { rbuf[t] += rbuf[t+s]; cbuf[t] += cbuf[t+s]; }
        __syncthreads();
    }
    if (t == 0) {
        sums[b]      = 1.f / (rbuf[0] + 1.f);
        sums[NN + b] = 1.f / (cbuf[0] + 1.f);
    }
}

// ---------------------------------------------------------------------------
// prep_norm: A1f[v][w] = (a[v][w]+d)*rs[v]   (rownorm(a+I))
//            A2f[v][w] = (a[w][v]+d)*cs[v]   (rownorm(a^T+I))
// ---------------------------------------------------------------------------
__global__ __launch_bounds__(256) void prep_norm(
    const float* __restrict__ a, const float* __restrict__ sums,
    float* __restrict__ A1f, float* __restrict__ A2f)
{
    int i = blockIdx.x * 256 + threadIdx.x;   // 25600 exact (100 blocks)
    int v = i / NN, w = i % NN;
    float d = (v == w) ? 1.f : 0.f;
    A1f[i] = (a[v*NN + w] + d) * sums[v];
    A2f[i] = (a[w*NN + v] + d) * sums[NN + v];
}

// ---------------------------------------------------------------------------
// prep_mm: Ab = alpha*I + alpha*beta*A + beta^2 * A@A   for A1f and A2f
// ---------------------------------------------------------------------------
__global__ __launch_bounds__(256) void prep_mm(
    const float* __restrict__ A1f, const float* __restrict__ A2f,
    float* __restrict__ Ab1f, float* __restrict__ Ab2f)
{
    int idx = blockIdx.x * 256 + threadIdx.x;   // 51200 exact (200 blocks)
    int mtx = idx / MAT;
    int i = idx % MAT;
    int v = i / NN, l = i % NN;
    const float* A = mtx ? A2f : A1f;
    float s = 0.f;
    for (int w = 0; w < NN; ++w) s = fmaf(A[v*NN + w], A[w*NN + l], s);
    float d = (v == l) ? ALPHA : 0.f;
    float o = d + ALPHA*BETA*A[i] + BETA*BETA*s;
    (mtx ? Ab2f : Ab1f)[i] = o;
}

// ---------------------------------------------------------------------------
// prep_pk: pack 5 shared A-operand matrices into PK layout.
// mtx 0: At1 = beta*A1f + alpha*I ; 1: At2 ; 2: Ab1f ; 3: Ab2f ; 4: a
// pk[k8][v][j] = pack(M[v][8k8+2j], M[v][8k8+2j+1])
// ---------------------------------------------------------------------------
__global__ __launch_bounds__(256) void prep_pk(
    const float* __restrict__ a, const float* __restrict__ A1f,
    const float* __restrict__ A2f, const float* __restrict__ Ab1f,
    const float* __restrict__ Ab2f,
    u32* __restrict__ At1pk, u32* __restrict__ At2pk,
    u32* __restrict__ Ah1pk, u32* __restrict__ Ah2pk, u32* __restrict__ apk)
{
    int idx = blockIdx.x * 256 + threadIdx.x;
    if (idx >= 5 * 3200) return;
    int mtx = idx / 3200;
    int r = idx % 3200;
    int k8 = r / 160, v = r % 160;
    const float* src = (mtx == 0) ? A1f : (mtx == 1) ? A2f :
                       (mtx == 2) ? Ab1f : (mtx == 3) ? Ab2f : a;
    u32 o[4];
    #pragma unroll
    for (int j = 0; j < 4; ++j) {
        int w0 = k8*8 + 2*j;
        float f0 = src[v*NN + w0], f1 = src[v*NN + w0 + 1];
        if (mtx <= 1) {
            f0 = BETA*f0 + ((v == w0)   ? ALPHA : 0.f);
            f1 = BETA*f1 + ((v == w0+1) ? ALPHA : 0.f);
        }
        o[j] = pk2(f0, f1);
    }
    u32* dst = (mtx == 0) ? At1pk : (mtx == 1) ? At2pk :
               (mtx == 2) ? Ah1pk : (mtx == 3) ? Ah2pk : apk;
    *(uint4*)&dst[(k8*160 + v)*4] = make_uint4(o[0], o[1], o[2], o[3]);
}

// ---------------------------------------------------------------------------
// cvt_x_pk: x fp32 [bc][v][l] -> PK (contraction dim = v):
//   xpk[bc][k8][l][j] = pack(x[8k8+2j][l], x[8k8+2j+1][l])
// one thread per uint4 (one (bc,k8,l))
// ---------------------------------------------------------------------------
__global__ __launch_bounds__(256) void cvt_x_pk(const float* __restrict__ x,
                                                u32* __restrict__ xpk)
{
    int idx = blockIdx.x * 256 + threadIdx.x;   // 3,276,800 (12800 blocks)
    int l  = idx % NN;
    int k8 = (idx / NN) % 20;
    int bc = idx / 3200;
    const float* xb = x + (size_t)bc * MAT + (size_t)(k8*8) * NN + l;
    u32 o[4];
    #pragma unroll
    for (int j = 0; j < 4; ++j)
        o[j] = pk2(xb[(2*j)*NN], xb[(2*j+1)*NN]);
    *(uint4*)&xpk[(size_t)bc * PKSZ + (size_t)(k8*160 + l)*4] =
        make_uint4(o[0], o[1], o[2], o[3]);
}

// ---------------------------------------------------------------------------
// bgemm16: per-block one bc. C[v][l] = sum_w A(v,w) * Q(w,l), MFMA 16x16x32 bf16.
// A, Q in PK layout. astride=0 for shared A, PKSZ for per-bc A.
// Cf: fp32 output (nullable); cacc: C += result; Cpk: PK output of raw result.
// 4 waves, each an 80x80 quadrant (5x5 tiles of 16x16), K-chunks of 32.
// ---------------------------------------------------------------------------
__global__ __launch_bounds__(256, 2) void bgemm16(
    const u32* __restrict__ Apk, long astride,
    const u32* __restrict__ Qpk,
    float* __restrict__ Cf, int cacc,
    u32* __restrict__ Cpk)
{
    __shared__ u32 As[2560];   // 4 k8-groups x 160 rows x 4 uints = 10240 B
    __shared__ u32 Bs[2560];
    int bc = blockIdx.x;
    int t = threadIdx.x;
    int lane = t & 63, w = t >> 6;
    int q = lane >> 4, ll = lane & 15;
    int v0w = (w >> 1) * 80, l0w = (w & 1) * 80;
    const u32* Ab = Apk + (size_t)bc * (size_t)astride;
    const u32* Qb = Qpk + (size_t)bc * PKSZ;

    f32x4 acc[5][5];
    #pragma unroll
    for (int rt = 0; rt < 5; ++rt)
        #pragma unroll
        for (int ct = 0; ct < 5; ++ct)
            acc[rt][ct] = (f32x4){0.f, 0.f, 0.f, 0.f};

    for (int c = 0; c < 5; ++c) {       // 5 K-chunks of 32
        __syncthreads();
        for (int i = t; i < 640; i += 256) {
            *(uint4*)&As[i*4] = *(const uint4*)&Ab[(size_t)c*2560 + i*4];
            *(uint4*)&Bs[i*4] = *(const uint4*)&Qb[(size_t)c*2560 + i*4];
        }
        __syncthreads();
        short8 af[5], bf[5];
        #pragma unroll
        for (int rt = 0; rt < 5; ++rt)
            af[rt] = *(const short8*)&As[(q*160 + v0w + rt*16 + ll)*4];
        #pragma unroll
        for (int ct = 0; ct < 5; ++ct)
            bf[ct] = *(const short8*)&Bs[(q*160 + l0w + ct*16 + ll)*4];
        #pragma unroll
        for (int rt = 0; rt < 5; ++rt)
            #pragma unroll
            for (int ct = 0; ct < 5; ++ct)
                acc[rt][ct] = __builtin_amdgcn_mfma_f32_16x16x32_bf16(
                    af[rt], bf[ct], acc[rt][ct], 0, 0, 0);
    }

    // epilogue: C/D layout col=lane&15, row=(lane>>4)*4+reg  [m89-verified]
    float* Cb = Cf  ? Cf  + (size_t)bc * MAT  : (float*)0;
    u32*   Pb = Cpk ? Cpk + (size_t)bc * PKSZ : (u32*)0;
    #pragma unroll
    for (int rt = 0; rt < 5; ++rt) {
        int vb = v0w + rt*16 + q*4;       // first of 4 consecutive rows
        #pragma unroll
        for (int ct = 0; ct < 5; ++ct) {
            int l = l0w + ct*16 + ll;
            f32x4 o = acc[rt][ct];
            if (Pb) {                     // PK of raw GEMM result
                int k8 = vb >> 3, j = (vb >> 1) & 3;
                size_t pa = (size_t)(k8*160 + l)*4 + j;
                Pb[pa]     = pk2(o.x, o.y);
                Pb[pa + 1] = pk2(o.z, o.w);
            }
            if (Cb) {
                size_t base = (size_t)vb * NN + l;
                if (cacc) {
                    o.x += Cb[base];
                    o.y += Cb[base + NN];
                    o.z += Cb[base + 2*NN];
                    o.w += Cb[base + 3*NN];
                }
                Cb[base]        = o.x;
                Cb[base + NN]   = o.y;
                Cb[base + 2*NN] = o.z;
                Cb[base + 3*NN] = o.w;
            }
        }
    }
}

// ---------------------------------------------------------------------------
// chanmix: thread handles v-pair (2v0, 2v0+1) at (b, l).
// embed emitted in PK layout (contraction dim = node v), pool in fp32.
// ---------------------------------------------------------------------------
__global__ __launch_bounds__(256) void chanmix(
    const float* __restrict__ x, const float* __restrict__ g1, const float* __restrict__ g2,
    const float* __restrict__ We, const float* __restrict__ be,
    const float* __restrict__ Wp, const float* __restrict__ bp,
    u32* __restrict__ embed_pk, float* __restrict__ pool)
{
    int idx = blockIdx.x * 256 + threadIdx.x;   // 409,600
    int l  = idx % NN;
    int v0 = (idx / NN) % 80;
    int b  = idx / (NN * 80);
    size_t base0 = (size_t)b * (32*MAT) + (size_t)(2*v0) * NN + l;
    size_t base1 = base0 + NN;
    const size_t coff = MAT;

    float e0[32], e1[32], p0[32], p1[32];
    #pragma unroll
    for (int o = 0; o < 32; ++o) {
        float b2e = 2.f * be[o], b2p = 2.f * bp[o];
        e0[o] = b2e; e1[o] = b2e; p0[o] = b2p; p1[o] = b2p;
    }
    #pragma unroll 1
    for (int k = 0; k < 3; ++k) {
        const float* s = (k == 0) ? x : ((k == 1) ? g1 : g2);
        float sc = (k == 0) ? 2.f : 1.f;
        #pragma unroll 1
        for (int c = 0; c < 32; ++c) {
            float h0 = s[base0 + (size_t)c*coff] * sc;
            float h1 = s[base1 + (size_t)c*coff] * sc;
            #pragma unroll
            for (int o = 0; o < 32; ++o) {
                float we = We[o*96 + k*32 + c];
                float wp = Wp[o*96 + k*32 + c];
                e0[o] = fmaf(we, h0, e0[o]);
                e1[o] = fmaf(we, h1, e1[o]);
                p0[o] = fmaf(wp, h0, p0[o]);
                p1[o] = fmaf(wp, h1, p1[o]);
            }
        }
    }
    int k8 = v0 >> 2, j = v0 & 3;
    #pragma unroll
    for (int o = 0; o < 32; ++o) {
        size_t bo = (size_t)(b*32 + o);
        pool[bo*MAT + (size_t)(2*v0)*NN + l]     = p0[o];
        pool[bo*MAT + (size_t)(2*v0+1)*NN + l]   = p1[o];
        embed_pk[bo*PKSZ + (size_t)(k8*160 + l)*4 + j] = pk2(e0[o], e1[o]);
    }
}

// ---------------------------------------------------------------------------
// softmax over node dim, in place; also emits srpk = PK over node-row pairs
// (serves both as B-operand of a@s and A-operand of s^T@embed).
// ---------------------------------------------------------------------------
__global__ __launch_bounds__(256) void softmax_n(float* __restrict__ p,
                                                 u32* __restrict__ srpk)
{
    int idx = blockIdx.x * 256 + threadIdx.x;   // 163,840 columns
    int l  = idx % NN;
    int bo = idx / NN;
    float* col = p + (size_t)bo * MAT + l;
    float m = -1e30f, s = 0.f;
    for (int n = 0; n < NN; ++n) {
        float v  = col[(size_t)n * NN];
        float mn = fmaxf(m, v);
        s = s * __expf(m - mn) + __expf(v - mn);
        m = mn;
    }
    float inv = 1.f / s;
    u32* sp = srpk + (size_t)bo * PKSZ;
    for (int k2 = 0; k2 < 80; ++k2) {
        float s0 = __expf(col[(size_t)(2*k2)   * NN] - m) * inv;
        float s1 = __expf(col[(size_t)(2*k2+1) * NN] - m) * inv;
        col[(size_t)(2*k2)   * NN] = s0;
        col[(size_t)(2*k2+1) * NN] = s1;
        sp[(size_t)((k2 >> 2)*160 + l)*4 + (k2 & 3)] = pk2(s0, s1);
    }
}

// ---------------------------------------------------------------------------
// tpack: scpk[bc][k8][v][j] = pack(s[v][8k8+2j], s[v][8k8+2j+1])
// (A-operand of a_new = s@M: contraction over s's columns)
// ---------------------------------------------------------------------------
__global__ __launch_bounds__(256) void tpack(const float* __restrict__ s,
                                             u32* __restrict__ scpk)
{
    int idx = blockIdx.x * 256 + threadIdx.x;   // 3,276,800 (12800 blocks)
    int v  = idx % NN;
    int k8 = (idx / NN) % 20;
    int bc = idx / 3200;
    const float* sb = s + (size_t)bc * MAT + (size_t)v * NN + k8*8;
    u32 o[4];
    #pragma unroll
    for (int j = 0; j < 4; ++j)
        o[j] = pk2(sb[2*j], sb[2*j + 1]);
    *(uint4*)&scpk[(size_t)bc * PKSZ + (size_t)(k8*160 + v)*4] =
        make_uint4(o[0], o[1], o[2], o[3]);
}

// ---------------------------------------------------------------------------
extern "C" void kernel_launch(void* const* d_in, const int* in_sizes, int n_in,
                              void* d_out, int out_size, void* d_ws, size_t ws_size,
                              hipStream_t stream)
{
    const float* x  = (const float*)d_in[0];
    const float* a  = (const float*)d_in[1];
    const float* We = (const float*)d_in[2];
    const float* be = (const float*)d_in[3];
    const float* Wp = (const float*)d_in[4];
    const float* bp = (const float*)d_in[5];

    float* part0 = (float*)d_out;          // pool -> s -> x_new
    float* part1 = part0 + BIG;            // h2a/G2 -> a_new

    char* ws = (char*)d_ws;
    // persistent small PK mats: 5 x 51200 B = 256,000 B
    u32* At1pk = (u32*)(ws + 0);
    u32* At2pk = (u32*)(ws + 51200);
    u32* Ah1pk = (u32*)(ws + 102400);
    u32* Ah2pk = (u32*)(ws + 153600);
    u32* apk   = (u32*)(ws + 204800);
    // big regions
    float* B1      = (float*)(ws + 256000);                 // 104,857,600 B: h1a/G1 -> srpk+scpk
    u32*   R3      = (u32*)  (ws + 256000 + 104857600);     //  52,428,800 B: x_pk -> embed_pk
    u32*   R4      = (u32*)  (ws + 256000 + 157286400);     //  52,428,800 B: M_pk
    // total: 209,971,200 B
    // prep-phase temps live inside B1 (dead before first bgemm writes B1)
    float* sums = B1;                       // 320 floats
    float* A1f  = (float*)((char*)B1 + 1536);
    float* A2f  = A1f + MAT;
    float* Ab1f = A2f + MAT;
    float* Ab2f = Ab1f + MAT;
    u32* x_pk     = R3;
    u32* embed_pk = R3;
    u32* srpk = (u32*)B1;
    u32* scpk = (u32*)((char*)B1 + 52428800);
    u32* M_pk = R4;

    // ---- prep (tiny) ----
    prep_sums<<<160, 256, 0, stream>>>(a, sums);
    prep_norm<<<100, 256, 0, stream>>>(a, sums, A1f, A2f);
    prep_mm  <<<200, 256, 0, stream>>>(A1f, A2f, Ab1f, Ab2f);
    prep_pk  <<<63, 256, 0, stream>>>(a, A1f, A2f, Ab1f, Ab2f,
                                      At1pk, At2pk, Ah1pk, Ah2pk, apk);
    cvt_x_pk <<<12800, 256, 0, stream>>>(x, x_pk);

    // ---- hop GEMMs (all read x_pk; h1 = At@x, h2 = Ah@x) ----
    bgemm16<<<BCN, 256, 0, stream>>>(At1pk, 0, x_pk, B1,    0, (u32*)0);  // h1a
    bgemm16<<<BCN, 256, 0, stream>>>(Ah1pk, 0, x_pk, part1, 0, (u32*)0);  // h2a
    bgemm16<<<BCN, 256, 0, stream>>>(At2pk, 0, x_pk, B1,    1, (u32*)0);  // G1 = h1a+h1b
    bgemm16<<<BCN, 256, 0, stream>>>(Ah2pk, 0, x_pk, part1, 1, (u32*)0);  // G2 = h2a+h2b

    // ---- channel mix + softmax + packs ----
    chanmix<<<1600, 256, 0, stream>>>(x, B1, part1, We, be, Wp, bp, embed_pk, part0);
    softmax_n<<<640, 256, 0, stream>>>(part0, srpk);
    tpack<<<12800, 256, 0, stream>>>(part0, scpk);

    // ---- output GEMMs ----
    // M = a@s (PK-only output)
    bgemm16<<<BCN, 256, 0, stream>>>(apk, 0, srpk, (float*)0, 0, M_pk);
    // x_new = s^T @ embed
    bgemm16<<<BCN, 256, 0, stream>>>(srpk, (long)PKSZ, embed_pk, part0, 0, (u32*)0);
    // a_new = s @ M
    bgemm16<<<BCN, 256, 0, stream>>>(scpk, (long)PKSZ, M_pk, part1, 0, (u32*)0);
}